// Round 3
// baseline (277.161 us; speedup 1.0000x reference)
//
#include <hip/hip_runtime.h>

#define HH 128
#define WW 128
#define CIN 64
#define COUT 64
#define NTAP 9

typedef __attribute__((ext_vector_type(8))) short bf16x8;   // 8 bf16 (4 VGPRs)
typedef __attribute__((ext_vector_type(4))) float f32x4;    // MFMA accumulator

#define XB_ROW   (130 * 64)                 // ushorts per (sample,row): 16640 B
#define XB_SAMP  (130 * XB_ROW)             // 130 rows (image rows -1..128)
#define XB_BYTES ((size_t)8 * XB_SAMP * 2)  // 17,305,600 B
#define WFRAG_BYTES (NTAP * 2 * 4 * 64 * 8 * 2)  // 73,728 B
#define XB_OFF   81920

__device__ inline ushort f2bf(float f) {
    union { float f; uint u; } v; v.f = f;
    uint u = v.u;
    return (ushort)((u + 0x7FFF + ((u >> 16) & 1)) >> 16);   // RNE
}

__device__ inline void gl_lds16(const void* g, void* l) {
    __builtin_amdgcn_global_load_lds(
        (const __attribute__((address_space(1))) unsigned int*)g,
        (__attribute__((address_space(3))) unsigned int*)l, 16, 0, 0);
}

// ---------------------------------------------------------------------------
// Prep W: pack weights into MFMA-fragment order, bf16.
// wfrag idx = (((tap*2 + ks)*4 + f)*64 + lane)*8 + j
//   co = f*16 + (lane&15); ci = ks*32 + (lane>>4)*8 + j
// ---------------------------------------------------------------------------
__global__ void prep_w(const float* __restrict__ weight, ushort* __restrict__ wfrag) {
    int idx = blockIdx.x * 256 + threadIdx.x;
    if (idx >= NTAP * 2 * 4 * 64 * 8) return;
    int j  = idx & 7;
    int l  = (idx >> 3) & 63;
    int f  = (idx >> 9) & 3;
    int ks = (idx >> 11) & 1;
    int tp = idx >> 12;
    int co = f * 16 + (l & 15);
    int ci = ks * 32 + (l >> 4) * 8 + j;
    wfrag[idx] = f2bf(weight[((size_t)co * CIN + ci) * NTAP + tp]);
}

// ---------------------------------------------------------------------------
// Prep X: transpose first 8 samples to bf16 [i][row -1..128][xs 0..129][ci],
// with the 16B-slot XOR swizzle (slot = (ci>>3)^(xs&7)) and zero padding
// (rows -1,128; cols xs=0,129) baked in. Enables linear global_load_lds.
// ---------------------------------------------------------------------------
__global__ __launch_bounds__(256) void prep_x(const float* __restrict__ x,
                                              ushort* __restrict__ xb) {
    const int blk = blockIdx.x;          // 0..1039
    const int i = blk / 130;
    const int r = blk % 130;             // xb row; image row = r-1
    ushort* dst = xb + (size_t)(i * 130 + r) * XB_ROW;
    const int ir = r - 1;
    if (ir < 0 || ir >= HH) {
        uint* d = (uint*)dst;
        for (int e = threadIdx.x; e < XB_ROW / 2; e += 256) d[e] = 0;
        return;
    }
    const float* xrow = x + ((size_t)i * CIN * HH + ir) * WW;
    for (int e = threadIdx.x; e < 130 * 64; e += 256) {
        int ci = e / 130, xs = e - ci * 130;
        float v = 0.f;
        if (xs >= 1 && xs <= 128) v = xrow[(size_t)ci * HH * WW + (xs - 1)];
        int slot = (ci >> 3) ^ (xs & 7);
        dst[xs * 64 + slot * 8 + (ci & 7)] = f2bf(v);
    }
}

// ---------------------------------------------------------------------------
// Fused kernel: 9216 blocks, 1:8 interleave.
//   bid%9==0 -> k1 (dense MFMA conv, 1024 blocks)
//   else     -> k2 (per-term single-channel conv, 8192 blocks, write-bound)
// ---------------------------------------------------------------------------
constexpr int K2_NCO = 16;

__global__ __launch_bounds__(256, 3) void fused(
    const float* __restrict__ x, const ushort* __restrict__ xb,
    const ushort* __restrict__ wfrag, const float* __restrict__ weight,
    const float* __restrict__ bias,
    const int* __restrict__ term_errors, const int* __restrict__ term_feats,
    float* __restrict__ out, int i_first)
{
    __shared__ __align__(16) char smem[3 * 130 * 64 * 2];   // 49920 B
    const int bid = blockIdx.x;
    const int q = bid / 9;
    const int t = threadIdx.x;

    if (bid - q * 9 == 0) {
        // ---------------- k1: dense conv via bf16 MFMA implicit GEMM -------
        const int k1id = q;
        const int i = k1id & 7;            // sample -> XCD locality (9%8==1)
        const int y = k1id >> 3;           // output row
        // rows y..y+2 of xb (image rows y-1..y+1) are contiguous: 49920 B
        const char* src = (const char*)(xb + (size_t)(i * 130 + y) * XB_ROW);
#pragma unroll
        for (int it = 0; it < 12; ++it)
            gl_lds16(src + it * 4096 + t * 16, smem + it * 4096 + t * 16);
        if (t < 48)
            gl_lds16(src + 49152 + t * 16, smem + 49152 + t * 16);
        __syncthreads();

        const ushort* A = (const ushort*)smem;
        const int wv = t >> 6;             // wave 0..3
        const int l  = t & 63;
        const int g  = l >> 4;
        const int ln = l & 15;
        const int xbase = wv * 32;

        f32x4 acc[4][2];
#pragma unroll
        for (int f = 0; f < 4; ++f)
#pragma unroll
            for (int xfi = 0; xfi < 2; ++xfi)
                acc[f][xfi] = (f32x4){0.f, 0.f, 0.f, 0.f};

        const bf16x8* Wp = (const bf16x8*)wfrag;
#pragma unroll
        for (int tap = 0; tap < NTAP; ++tap) {
            const int kh = tap / 3, kw = tap % 3;
            bf16x8 wf[2][4];
#pragma unroll
            for (int ks = 0; ks < 2; ++ks)
#pragma unroll
                for (int f = 0; f < 4; ++f)
                    wf[ks][f] = Wp[((tap * 2 + ks) * 4 + f) * 64 + l];
            bf16x8 xf_[2][2];
#pragma unroll
            for (int xfi = 0; xfi < 2; ++xfi)
#pragma unroll
                for (int ks = 0; ks < 2; ++ks) {
                    int xs = xbase + xfi * 16 + ln + kw;   // 0..129
                    int slot = (ks * 4 + g) ^ (xs & 7);
                    xf_[xfi][ks] = *(const bf16x8*)(A + (size_t)(kh * 130 + xs) * 64 + slot * 8);
                }
#pragma unroll
            for (int f = 0; f < 4; ++f)
#pragma unroll
                for (int xfi = 0; xfi < 2; ++xfi)
#pragma unroll
                    for (int ks = 0; ks < 2; ++ks)
                        acc[f][xfi] = __builtin_amdgcn_mfma_f32_16x16x32_bf16(
                            wf[ks][f], xf_[xfi][ks], acc[f][xfi], 0, 0, 0);
        }

#pragma unroll
        for (int f = 0; f < 4; ++f) {
#pragma unroll
            for (int r = 0; r < 4; ++r) {
                int co = f * 16 + g * 4 + r;
                float b = (i == 0) ? bias[co] : 0.f;
#pragma unroll
                for (int xfi = 0; xfi < 2; ++xfi) {
                    int xcol = xbase + xfi * 16 + ln;
                    out[(((size_t)i * COUT + co) * HH + y) * WW + xcol] = acc[f][xfi][r] + b;
                }
            }
        }
    } else {
        // ---------------- k2: per-term single-channel conv (write-bound) ---
        const int k2id = bid - q - 1;      // 8q + (s-1), bijective 0..8191
        const int tt    = k2id >> 6;
        const int sub   = k2id & 63;
        const int strip = sub & 15;
        const int cog   = sub >> 4;
        const int e = term_errors[tt];
        const int f = term_feats[tt];
        const float* xp = x + ((size_t)e * CIN + f) * HH * WW;
        const int y0 = strip * 8;

        float (*tile)[132] = (float(*)[132])smem;
        for (int idx = t; idx < 10 * 130; idx += 256) {
            int gy = idx / 130, gx = idx - gy * 130;
            int yy = y0 + gy - 1, xx = gx - 1;
            float v = 0.f;
            if (yy >= 0 && yy < HH && xx >= 0 && xx < WW) v = xp[yy * WW + xx];
            tile[gy][gx] = v;
        }
        __syncthreads();

        const int r  = t >> 5;
        const int cq = (t & 31) * 4;
        float xv[3][6];
#pragma unroll
        for (int kh = 0; kh < 3; ++kh)
#pragma unroll
            for (int j = 0; j < 6; ++j)
                xv[kh][j] = tile[r + kh][cq + j];

        const int oy = y0 + r;
#pragma unroll
        for (int c = 0; c < K2_NCO; ++c) {
            int co = cog * K2_NCO + c;
            const float* wc = weight + ((size_t)co * CIN + f) * 9;
            float op[4];
#pragma unroll
            for (int p = 0; p < 4; ++p) {
                float s = 0.f;
#pragma unroll
                for (int kh = 0; kh < 3; ++kh)
#pragma unroll
                    for (int kw = 0; kw < 3; ++kw)
                        s = fmaf(xv[kh][p + kw], wc[kh * 3 + kw], s);
                op[p] = s;
            }
            float4* dst = (float4*)&out[
                ((((size_t)(i_first + tt)) * COUT + co) * HH + oy) * WW + cq];
            *dst = make_float4(op[0], op[1], op[2], op[3]);
        }
    }
}

// ---------------------------------------------------------------------------
// Fallback path (round-2 kernels) if ws_size is too small for xb.
// ---------------------------------------------------------------------------
__global__ __launch_bounds__(256, 3) void conv_first_mfma_fb(
    const float* __restrict__ x, const ushort* __restrict__ wfrag,
    const float* __restrict__ bias, float* __restrict__ out)
{
    __shared__ ushort A[3 * 130 * 64];
    const int wg = (blockIdx.x & 7) * 128 + (blockIdx.x >> 3);
    const int i = wg >> 7;
    const int y = wg & 127;
    const int t = threadIdx.x;
    {
        uint* Az = (uint*)A;
        for (int e = t; e < 6 * 32; e += 256) {
            int rr = e >> 5;
            int kh = rr >> 1;
            int xs = (rr & 1) ? 129 : 0;
            Az[(kh * 130 + xs) * 32 + (e & 31)] = 0;
        }
    }
    const float* xi = x + (size_t)i * CIN * HH * WW;
    for (int it = 0; it < 48; ++it) {
        int flat = it * 256 + t;
        int xs = (flat & 127) + 1;
        int cp = (flat >> 7) & 31;
        int kh = flat >> 12;
        int yy = y + kh - 1;
        uint v = 0;
        if (yy >= 0 && yy < HH) {
            const float* p = xi + ((size_t)(2 * cp) * HH + yy) * WW + (xs - 1);
            v = (uint)f2bf(p[0]) | ((uint)f2bf(p[HH * WW]) << 16);
        }
        int slot = (cp >> 2) ^ (xs & 7);
        ((uint*)A)[(kh * 130 + xs) * 32 + slot * 4 + (cp & 3)] = v;
    }
    __syncthreads();

    const int wv = t >> 6;
    const int l  = t & 63;
    const int g  = l >> 4;
    const int ln = l & 15;
    const int xbase = wv * 32;
    f32x4 acc[4][2];
#pragma unroll
    for (int f = 0; f < 4; ++f)
#pragma unroll
        for (int xfi = 0; xfi < 2; ++xfi)
            acc[f][xfi] = (f32x4){0.f, 0.f, 0.f, 0.f};
    const bf16x8* Wp = (const bf16x8*)wfrag;
#pragma unroll
    for (int tap = 0; tap < NTAP; ++tap) {
        const int kh = tap / 3, kw = tap % 3;
        bf16x8 wf[2][4];
#pragma unroll
        for (int ks = 0; ks < 2; ++ks)
#pragma unroll
            for (int f = 0; f < 4; ++f)
                wf[ks][f] = Wp[((tap * 2 + ks) * 4 + f) * 64 + l];
        bf16x8 xf_[2][2];
#pragma unroll
        for (int xfi = 0; xfi < 2; ++xfi)
#pragma unroll
            for (int ks = 0; ks < 2; ++ks) {
                int xs = xbase + xfi * 16 + ln + kw;
                int slot = (ks * 4 + g) ^ (xs & 7);
                xf_[xfi][ks] = *(const bf16x8*)(A + (size_t)(kh * 130 + xs) * 64 + slot * 8);
            }
#pragma unroll
        for (int f = 0; f < 4; ++f)
#pragma unroll
            for (int xfi = 0; xfi < 2; ++xfi)
#pragma unroll
                for (int ks = 0; ks < 2; ++ks)
                    acc[f][xfi] = __builtin_amdgcn_mfma_f32_16x16x32_bf16(
                        wf[ks][f], xf_[xfi][ks], acc[f][xfi], 0, 0, 0);
    }
#pragma unroll
    for (int f = 0; f < 4; ++f)
#pragma unroll
        for (int r = 0; r < 4; ++r) {
            int co = f * 16 + g * 4 + r;
            float b = (i == 0) ? bias[co] : 0.f;
#pragma unroll
            for (int xfi = 0; xfi < 2; ++xfi) {
                int xcol = xbase + xfi * 16 + ln;
                out[(((size_t)i * COUT + co) * HH + y) * WW + xcol] = acc[f][xfi][r] + b;
            }
        }
}

__global__ __launch_bounds__(256) void conv_terms_fb(
    const float* __restrict__ x, const float* __restrict__ weight,
    const int* __restrict__ term_errors, const int* __restrict__ term_feats,
    float* __restrict__ out, int i_first)
{
    __shared__ float tile[10][132];
    const int tt    = blockIdx.y;
    const int strip = blockIdx.x & 15;
    const int cog   = blockIdx.x >> 4;
    const int e = term_errors[tt];
    const int f = term_feats[tt];
    const float* xp = x + ((size_t)e * CIN + f) * HH * WW;
    const int y0 = strip * 8;
    for (int idx = threadIdx.x; idx < 10 * 130; idx += 256) {
        int gy = idx / 130, gx = idx % 130;
        int yy = y0 + gy - 1, xx = gx - 1;
        float v = 0.f;
        if (yy >= 0 && yy < HH && xx >= 0 && xx < WW) v = xp[yy * WW + xx];
        tile[gy][gx] = v;
    }
    __syncthreads();
    const int r  = threadIdx.x >> 5;
    const int cq = (threadIdx.x & 31) * 4;
    float xv[3][6];
#pragma unroll
    for (int kh = 0; kh < 3; ++kh)
#pragma unroll
        for (int j = 0; j < 6; ++j)
            xv[kh][j] = tile[r + kh][cq + j];
    const int oy = y0 + r;
#pragma unroll
    for (int c = 0; c < K2_NCO; ++c) {
        int co = cog * K2_NCO + c;
        const float* wc = weight + ((size_t)co * CIN + f) * 9;
        float op[4];
#pragma unroll
        for (int p = 0; p < 4; ++p) {
            float s = 0.f;
#pragma unroll
            for (int kh = 0; kh < 3; ++kh)
#pragma unroll
                for (int kw = 0; kw < 3; ++kw)
                    s = fmaf(xv[kh][p + kw], wc[kh * 3 + kw], s);
            op[p] = s;
        }
        float4* dst = (float4*)&out[
            ((((size_t)(i_first + tt)) * COUT + co) * HH + oy) * WW + cq];
        *dst = make_float4(op[0], op[1], op[2], op[3]);
    }
}

extern "C" void kernel_launch(void* const* d_in, const int* in_sizes, int n_in,
                              void* d_out, int out_size, void* d_ws, size_t ws_size,
                              hipStream_t stream) {
    const float* x          = (const float*)d_in[0];
    const float* weight     = (const float*)d_in[1];
    const float* bias       = (const float*)d_in[2];
    const int* term_errors  = (const int*)d_in[3];
    const int* term_feats   = (const int*)d_in[4];
    float* out = (float*)d_out;
    ushort* wfrag = (ushort*)d_ws;

    const int T = in_sizes[3];                      // 128
    const int n_out = out_size / (COUT * HH * WW);  // 136
    const int i_first = n_out - T;                  // 8

    prep_w<<<(NTAP * 2 * 4 * 64 * 8 + 255) / 256, 256, 0, stream>>>(weight, wfrag);

    if (ws_size >= XB_OFF + XB_BYTES) {
        ushort* xb = (ushort*)((char*)d_ws + XB_OFF);
        prep_x<<<i_first * 130, 256, 0, stream>>>(x, xb);
        const int n1 = i_first * HH;                // 1024
        fused<<<n1 * 9, 256, 0, stream>>>(x, xb, wfrag, weight, bias,
                                          term_errors, term_feats, out, i_first);
    } else {
        conv_first_mfma_fb<<<i_first * HH, 256, 0, stream>>>(x, wfrag, bias, out);
        dim3 g2(16 * (COUT / K2_NCO), T);
        conv_terms_fb<<<g2, 256, 0, stream>>>(x, weight, term_errors, term_feats,
                                              out, i_first);
    }
}

// Round 4
// 170.148 us; speedup vs baseline: 1.6289x; 1.6289x over previous
//
#include <hip/hip_runtime.h>

#define HH 128
#define WW 128
#define CIN 64
#define COUT 64
#define NTAP 9

typedef __attribute__((ext_vector_type(8))) short bf16x8;   // 8 bf16 (4 VGPRs)
typedef __attribute__((ext_vector_type(4))) float f32x4;    // MFMA accumulator

#define XB_ROW_US (130 * 64)                    // ushorts per (sample,row) = 16640 B
#define XB_BYTES  ((size_t)8 * 130 * XB_ROW_US * 2)  // 17,305,600 B
#define XB_OFF    81920

__device__ inline ushort f2bf(float f) {
    union { float f; uint u; } v; v.f = f;
    uint u = v.u;
    return (ushort)((u + 0x7FFF + ((u >> 16) & 1)) >> 16);   // RNE
}

// ---------------------------------------------------------------------------
// Prep W: pack weights into MFMA-fragment order, bf16.
// wfrag idx = (((tap*2 + ks)*4 + f)*64 + lane)*8 + j
//   co = f*16 + (lane&15); ci = ks*32 + (lane>>4)*8 + j
// ---------------------------------------------------------------------------
__global__ void prep_w(const float* __restrict__ weight, ushort* __restrict__ wfrag) {
    int idx = blockIdx.x * 256 + threadIdx.x;
    if (idx >= NTAP * 2 * 4 * 64 * 8) return;
    int j  = idx & 7;
    int l  = (idx >> 3) & 63;
    int f  = (idx >> 9) & 3;
    int ks = (idx >> 11) & 1;
    int tp = idx >> 12;
    int co = f * 16 + (l & 15);
    int ci = ks * 32 + (l >> 4) * 8 + j;
    wfrag[idx] = f2bf(weight[((size_t)co * CIN + ci) * NTAP + tp]);
}

// ---------------------------------------------------------------------------
// Prep X: transpose first 8 samples to PLAIN bf16 [i][row -1..128][xs 0..129][ci]
// (zero padding baked in). Transpose goes through an LDS tile with row stride
// 33 dwords (conflict-free writes, ~2-way reads), copy-out is coalesced uints.
// ---------------------------------------------------------------------------
__global__ __launch_bounds__(256) void prep_x(const float* __restrict__ x,
                                              ushort* __restrict__ xb) {
    __shared__ uint tile[130 * 33];      // [xs][cp], stride 33 dwords
    const int blk = blockIdx.x;          // 0..1039
    const int i = blk / 130;
    const int r = blk % 130;             // xb row; image row = r-1
    uint* dst = (uint*)(xb + (size_t)(i * 130 + r) * XB_ROW_US);  // 4160 uints
    const int ir = r - 1;
    if (ir < 0 || ir >= HH) {
        for (int e = threadIdx.x; e < 4160; e += 256) dst[e] = 0;
        return;
    }
    const float* xrow = x + ((size_t)i * CIN * HH + ir) * WW;
    // phase 1: [cp 0..31][xs 0..129]; lanes ~consecutive xs -> coalesced reads,
    // LDS uint writes at stride-33 rows -> conflict-free.
    for (int e = threadIdx.x; e < 32 * 130; e += 256) {
        int cp = e / 130;
        int xs = e - cp * 130;
        uint v = 0;
        if (xs >= 1 && xs <= 128) {
            const float* p = xrow + (size_t)(2 * cp) * HH * WW + (xs - 1);
            v = (uint)f2bf(p[0]) | ((uint)f2bf(p[HH * WW]) << 16);
        }
        tile[xs * 33 + cp] = v;
    }
    __syncthreads();
    // phase 2: linear coalesced copy-out; LDS banks = (xs + cp) % 32 -> 2-way free
    for (int e = threadIdx.x; e < 4160; e += 256) {
        int xs = e >> 5, cp = e & 31;
        dst[e] = tile[xs * 33 + cp];
    }
}

// ---------------------------------------------------------------------------
// Kernel 1: dense conv via bf16 MFMA implicit GEMM, NO LDS.
// A-fragments are contiguous b128 per-lane loads straight from plain xb
// (sample-per-XCD L2-resident). 1024 blocks: i = bid&7 (XCD), y = bid>>3.
// ---------------------------------------------------------------------------
__global__ __launch_bounds__(256, 3) void conv_first_direct(
    const ushort* __restrict__ xb, const ushort* __restrict__ wfrag,
    const float* __restrict__ bias, float* __restrict__ out)
{
    const int bid = blockIdx.x;
    const int i = bid & 7;                 // sample -> XCD locality
    const int y = bid >> 3;                // output row
    const int t = threadIdx.x;
    const int wv = t >> 6;                 // wave 0..3
    const int l  = t & 63;
    const int g  = l >> 4;                 // k-group
    const int ln = l & 15;
    const int xbase = wv * 32;

    f32x4 acc[4][2];
#pragma unroll
    for (int f = 0; f < 4; ++f)
#pragma unroll
        for (int xfi = 0; xfi < 2; ++xfi)
            acc[f][xfi] = (f32x4){0.f, 0.f, 0.f, 0.f};

    const bf16x8* Wp = (const bf16x8*)wfrag;
    const ushort* Ab = xb + (size_t)(i * 130 + y) * XB_ROW_US;  // rows y..y+2

#pragma unroll
    for (int tap = 0; tap < NTAP; ++tap) {
        const int kh = tap / 3, kw = tap % 3;
        bf16x8 wf[2][4];
#pragma unroll
        for (int ks = 0; ks < 2; ++ks)
#pragma unroll
            for (int f = 0; f < 4; ++f)
                wf[ks][f] = Wp[((tap * 2 + ks) * 4 + f) * 64 + l];
        bf16x8 xf_[2][2];
#pragma unroll
        for (int xfi = 0; xfi < 2; ++xfi)
#pragma unroll
            for (int ks = 0; ks < 2; ++ks) {
                int xs = xbase + xfi * 16 + ln + kw;   // 0..129
                xf_[xfi][ks] = *(const bf16x8*)(
                    Ab + (size_t)(kh * 130 + xs) * 64 + ks * 32 + g * 8);
            }
#pragma unroll
        for (int f = 0; f < 4; ++f)
#pragma unroll
            for (int xfi = 0; xfi < 2; ++xfi)
#pragma unroll
                for (int ks = 0; ks < 2; ++ks)
                    acc[f][xfi] = __builtin_amdgcn_mfma_f32_16x16x32_bf16(
                        wf[ks][f], xf_[xfi][ks], acc[f][xfi], 0, 0, 0);
    }

    // D: row = co = f*16 + g*4 + r ; col = x = xbase + xfi*16 + ln
#pragma unroll
    for (int f = 0; f < 4; ++f) {
#pragma unroll
        for (int r = 0; r < 4; ++r) {
            int co = f * 16 + g * 4 + r;
            float b = (i == 0) ? bias[co] : 0.f;
#pragma unroll
            for (int xfi = 0; xfi < 2; ++xfi) {
                int xcol = xbase + xfi * 16 + ln;
                out[(((size_t)i * COUT + co) * HH + y) * WW + xcol] = acc[f][xfi][r] + b;
            }
        }
    }
}

// ---------------------------------------------------------------------------
// Kernel 2: per-term single-channel convs — UNCHANGED from round 2.
// ---------------------------------------------------------------------------
constexpr int K2_NCO = 16;

__global__ __launch_bounds__(256) void conv_terms(
    const float* __restrict__ x, const float* __restrict__ weight,
    const int* __restrict__ term_errors, const int* __restrict__ term_feats,
    float* __restrict__ out, int i_first)
{
    __shared__ float tile[10][132];
    const int t     = blockIdx.y;
    const int strip = blockIdx.x & 15;
    const int cog   = blockIdx.x >> 4;
    const int e = term_errors[t];
    const int f = term_feats[t];
    const float* xp = x + ((size_t)e * CIN + f) * HH * WW;
    const int y0 = strip * 8;

    for (int idx = threadIdx.x; idx < 10 * 130; idx += 256) {
        int gy = idx / 130, gx = idx % 130;
        int yy = y0 + gy - 1, xx = gx - 1;
        float v = 0.f;
        if (yy >= 0 && yy < HH && xx >= 0 && xx < WW) v = xp[yy * WW + xx];
        tile[gy][gx] = v;
    }
    __syncthreads();

    const int r  = threadIdx.x >> 5;
    const int cq = (threadIdx.x & 31) * 4;

    float xv[3][6];
#pragma unroll
    for (int kh = 0; kh < 3; ++kh)
#pragma unroll
        for (int j = 0; j < 6; ++j)
            xv[kh][j] = tile[r + kh][cq + j];

    const int oy = y0 + r;
#pragma unroll
    for (int c = 0; c < K2_NCO; ++c) {
        int co = cog * K2_NCO + c;
        const float* wc = weight + ((size_t)co * CIN + f) * 9;
        float op[4];
#pragma unroll
        for (int p = 0; p < 4; ++p) {
            float s = 0.f;
#pragma unroll
            for (int kh = 0; kh < 3; ++kh)
#pragma unroll
                for (int kw = 0; kw < 3; ++kw)
                    s = fmaf(xv[kh][p + kw], wc[kh * 3 + kw], s);
            op[p] = s;
        }
        float4* dst = (float4*)&out[
            ((((size_t)(i_first + t)) * COUT + co) * HH + oy) * WW + cq];
        *dst = make_float4(op[0], op[1], op[2], op[3]);
    }
}

// ---------------------------------------------------------------------------
// Fallback k1 (round-2 inline-staging kernel) if ws_size too small for xb.
// ---------------------------------------------------------------------------
__global__ __launch_bounds__(256, 3) void conv_first_mfma_fb(
    const float* __restrict__ x, const ushort* __restrict__ wfrag,
    const float* __restrict__ bias, float* __restrict__ out)
{
    __shared__ ushort A[3 * 130 * 64];
    const int wg = (blockIdx.x & 7) * 128 + (blockIdx.x >> 3);
    const int i = wg >> 7;
    const int y = wg & 127;
    const int t = threadIdx.x;
    {
        uint* Az = (uint*)A;
        for (int e = t; e < 6 * 32; e += 256) {
            int rr = e >> 5;
            int kh = rr >> 1;
            int xs = (rr & 1) ? 129 : 0;
            Az[(kh * 130 + xs) * 32 + (e & 31)] = 0;
        }
    }
    const float* xi = x + (size_t)i * CIN * HH * WW;
    for (int it = 0; it < 48; ++it) {
        int flat = it * 256 + t;
        int xs = (flat & 127) + 1;
        int cp = (flat >> 7) & 31;
        int kh = flat >> 12;
        int yy = y + kh - 1;
        uint v = 0;
        if (yy >= 0 && yy < HH) {
            const float* p = xi + ((size_t)(2 * cp) * HH + yy) * WW + (xs - 1);
            v = (uint)f2bf(p[0]) | ((uint)f2bf(p[HH * WW]) << 16);
        }
        int slot = (cp >> 2) ^ (xs & 7);
        ((uint*)A)[(kh * 130 + xs) * 32 + slot * 4 + (cp & 3)] = v;
    }
    __syncthreads();

    const int wv = t >> 6;
    const int l  = t & 63;
    const int g  = l >> 4;
    const int ln = l & 15;
    const int xbase = wv * 32;
    f32x4 acc[4][2];
#pragma unroll
    for (int f = 0; f < 4; ++f)
#pragma unroll
        for (int xfi = 0; xfi < 2; ++xfi)
            acc[f][xfi] = (f32x4){0.f, 0.f, 0.f, 0.f};
    const bf16x8* Wp = (const bf16x8*)wfrag;
#pragma unroll
    for (int tap = 0; tap < NTAP; ++tap) {
        const int kh = tap / 3, kw = tap % 3;
        bf16x8 wf[2][4];
#pragma unroll
        for (int ks = 0; ks < 2; ++ks)
#pragma unroll
            for (int f = 0; f < 4; ++f)
                wf[ks][f] = Wp[((tap * 2 + ks) * 4 + f) * 64 + l];
        bf16x8 xf_[2][2];
#pragma unroll
        for (int xfi = 0; xfi < 2; ++xfi)
#pragma unroll
            for (int ks = 0; ks < 2; ++ks) {
                int xs = xbase + xfi * 16 + ln + kw;
                int slot = (ks * 4 + g) ^ (xs & 7);
                xf_[xfi][ks] = *(const bf16x8*)(A + (size_t)(kh * 130 + xs) * 64 + slot * 8);
            }
#pragma unroll
        for (int f = 0; f < 4; ++f)
#pragma unroll
            for (int xfi = 0; xfi < 2; ++xfi)
#pragma unroll
                for (int ks = 0; ks < 2; ++ks)
                    acc[f][xfi] = __builtin_amdgcn_mfma_f32_16x16x32_bf16(
                        wf[ks][f], xf_[xfi][ks], acc[f][xfi], 0, 0, 0);
    }
#pragma unroll
    for (int f = 0; f < 4; ++f)
#pragma unroll
        for (int r = 0; r < 4; ++r) {
            int co = f * 16 + g * 4 + r;
            float b = (i == 0) ? bias[co] : 0.f;
#pragma unroll
            for (int xfi = 0; xfi < 2; ++xfi) {
                int xcol = xbase + xfi * 16 + ln;
                out[(((size_t)i * COUT + co) * HH + y) * WW + xcol] = acc[f][xfi][r] + b;
            }
        }
}

extern "C" void kernel_launch(void* const* d_in, const int* in_sizes, int n_in,
                              void* d_out, int out_size, void* d_ws, size_t ws_size,
                              hipStream_t stream) {
    const float* x          = (const float*)d_in[0];
    const float* weight     = (const float*)d_in[1];
    const float* bias       = (const float*)d_in[2];
    const int* term_errors  = (const int*)d_in[3];
    const int* term_feats   = (const int*)d_in[4];
    float* out = (float*)d_out;
    ushort* wfrag = (ushort*)d_ws;

    const int T = in_sizes[3];                      // 128
    const int n_out = out_size / (COUT * HH * WW);  // 136
    const int i_first = n_out - T;                  // 8

    prep_w<<<(NTAP * 2 * 4 * 64 * 8 + 255) / 256, 256, 0, stream>>>(weight, wfrag);

    if (ws_size >= XB_OFF + XB_BYTES) {
        ushort* xb = (ushort*)((char*)d_ws + XB_OFF);
        prep_x<<<i_first * 130, 256, 0, stream>>>(x, xb);
        conv_first_direct<<<i_first * HH, 256, 0, stream>>>(xb, wfrag, bias, out);
    } else {
        conv_first_mfma_fb<<<i_first * HH, 256, 0, stream>>>(x, wfrag, bias, out);
    }

    dim3 g2(16 * (COUT / K2_NCO), T);
    conv_terms<<<g2, 256, 0, stream>>>(x, weight, term_errors, term_feats,
                                       out, i_first);
}